// Round 9
// baseline (1302.070 us; speedup 1.0000x reference)
//
#include <hip/hip_runtime.h>
#include <hip/hip_bf16.h>

#define FD 128   // IN == HID == 128
#define OD 64    // OUT

typedef __hip_bfloat16 bf16;

__device__ __forceinline__ float b2f(bf16 x) { return __bfloat162float(x); }
__device__ __forceinline__ float ldf(const float* p, size_t i) { return p[i]; }
__device__ __forceinline__ float ldf(const bf16* p, size_t i) { return __bfloat162float(p[i]); }

// ---------- dtype sniffer: bf16 data -> sane exponents; fp32 read as u16 -> garbage ----------
__global__ void k_sniff(const unsigned short* w1raw, unsigned* flag) {
    int t = threadIdx.x;                 // 64 threads
    int insane = 0;
    for (int i = t; i < 128; i += 64) {
        unsigned e = (w1raw[i] >> 7) & 0xFF;
        if (e != 0 && (e < 100 || e > 140)) insane++;
    }
    for (int o = 32; o > 0; o >>= 1) insane += __shfl_down(insane, o);
    if (t == 0) *flag = (insane > 16) ? 1u : 0u;   // 0 = bf16 world, 1 = fp32 world
}

// ---------- degree count ----------
__global__ void k_deg(const int* __restrict__ src, const int* __restrict__ dst,
                      unsigned* __restrict__ deg_s, unsigned* __restrict__ deg_d, int E) {
    int i = blockIdx.x * blockDim.x + threadIdx.x;
    if (i < E) {
        atomicAdd(&deg_s[src[i]], 1u);
        atomicAdd(&deg_d[dst[i]], 1u);
    }
}

// ---------- c = rsqrt(max(deg,1)) ----------
__global__ void k_cnorm(const unsigned* __restrict__ deg_s, const unsigned* __restrict__ deg_d,
                        float* __restrict__ c_src, float* __restrict__ c_dst, int n) {
    int i = blockIdx.x * blockDim.x + threadIdx.x;
    if (i < n) {
        c_src[i] = rsqrtf(fmaxf((float)deg_s[i], 1.0f));
        c_dst[i] = rsqrtf(fmaxf((float)deg_d[i], 1.0f));
    }
}

// ---------- wsum[s] = sum over out-edges of c_dst[dst] ----------
__global__ void k_wsum(const int* __restrict__ src, const int* __restrict__ dst,
                       const float* __restrict__ c_dst, float* __restrict__ wsum, int E) {
    int e = blockIdx.x * blockDim.x + threadIdx.x;
    if (e < E) unsafeAtomicAdd(&wsum[src[e]], c_dst[dst[e]]);
}

// ---------- scan stage 1: per-block sums of in-degree ----------
__global__ void k_scan1(const unsigned* __restrict__ deg, unsigned* __restrict__ bsum, int n) {
    __shared__ unsigned red[256];
    int t = threadIdx.x, i = blockIdx.x * 256 + t;
    red[t] = (i < n) ? deg[i] : 0u;
    __syncthreads();
    for (int o = 128; o > 0; o >>= 1) {
        if (t < o) red[t] += red[t + o];
        __syncthreads();
    }
    if (t == 0) bsum[blockIdx.x] = red[0];
}

// ---------- scan stage 2: exclusive scan of block sums (single block, 512 thr) ----------
__global__ void k_scan2(const unsigned* __restrict__ bsum, unsigned* __restrict__ bpre, int nb) {
    __shared__ unsigned s[512];
    int t = threadIdx.x;
    unsigned v = (t < nb) ? bsum[t] : 0u;
    s[t] = v;
    __syncthreads();
    for (int o = 1; o < 512; o <<= 1) {
        unsigned x = (t >= o) ? s[t - o] : 0u;
        __syncthreads();
        s[t] += x;
        __syncthreads();
    }
    if (t < nb) bpre[t] = s[t] - v;
}

// ---------- scan stage 3: row_ptr + cursor ----------
__global__ void k_scan3(const unsigned* __restrict__ deg, const unsigned* __restrict__ bpre,
                        unsigned* __restrict__ row_ptr, unsigned* __restrict__ cursor,
                        int n, int E) {
    __shared__ unsigned s[256];
    int t = threadIdx.x, i = blockIdx.x * 256 + t;
    unsigned v = (i < n) ? deg[i] : 0u;
    s[t] = v;
    __syncthreads();
    for (int o = 1; o < 256; o <<= 1) {
        unsigned x = (t >= o) ? s[t - o] : 0u;
        __syncthreads();
        s[t] += x;
        __syncthreads();
    }
    unsigned excl = bpre[blockIdx.x] + s[t] - v;
    if (i < n) { row_ptr[i] = excl; cursor[i] = excl; }
    if (blockIdx.x == 0 && t == 0) row_ptr[n] = (unsigned)E;
}

// ---------- CSR fill: col[] = src sorted by dst ----------
__global__ void k_fill(const int* __restrict__ src, const int* __restrict__ dst,
                       unsigned* __restrict__ cursor, unsigned* __restrict__ col, int E) {
    int e = blockIdx.x * blockDim.x + threadIdx.x;
    if (e < E) {
        unsigned p = atomicAdd(&cursor[dst[e]], 1u);
        col[p] = (unsigned)src[e];
    }
}

// ---------- layer1 fused: gather + GEMM + relu + weighted global reduce ----------
// SINGLE CHANGE vs round 8: 4 nodes/pass (16 passes); half h gathers+computes rows 2h,2h+1;
// gather unroll ladder x8/x4/scalar; GEMM k-blocked x4 with alignas(16) float4 xs reads.
template <typename T>
__global__ __launch_bounds__(256) void k_layer1(const unsigned* __restrict__ flag, unsigned want,
                                                const T* __restrict__ feat, const T* __restrict__ W1,
                                                const T* __restrict__ b1,
                                                const float* __restrict__ c_src,
                                                const float* __restrict__ c_dst,
                                                const float* __restrict__ wsum,
                                                const unsigned* __restrict__ row_ptr,
                                                const unsigned* __restrict__ col,
                                                float* __restrict__ accum128, int n) {
    if (*flag != want) return;
    __shared__ bf16 Wl[FD * FD];                  // 32 KB
    __shared__ float b1l[FD];
    __shared__ __align__(16) float xs[4][FD];     // 16B-aligned: float4 LDS reads below
    __shared__ float part[2][FD];
    int t = threadIdx.x;
    for (int i = t; i < FD * FD; i += 256) Wl[i] = __float2bfloat16(ldf(W1, i));
    if (t < FD) b1l[t] = ldf(b1, t);
    __syncthreads();

    int j = t & 127, half = t >> 7;
    int base = blockIdx.x * 64;
    float psum = 0.0f;                            // register partial for this thread
    for (int p = 0; p < 16; p++) {
        // ---- gather: half h fills rows 2h, 2h+1 ----
        #pragma unroll
        for (int rr = 0; rr < 2; rr++) {
            int r = half * 2 + rr;
            int node = base + p * 4 + r;
            float acc = 0.0f;
            if (node < n) {
                unsigned q = row_ptr[node], end = row_ptr[node + 1];
                for (; q + 8 <= end; q += 8) {   // x8: eight independent gather loads in flight
                    unsigned s0 = col[q],     s1 = col[q + 1], s2 = col[q + 2], s3 = col[q + 3];
                    unsigned s4 = col[q + 4], s5 = col[q + 5], s6 = col[q + 6], s7 = col[q + 7];
                    float f0 = ldf(feat, (size_t)s0 * FD + j);
                    float f1 = ldf(feat, (size_t)s1 * FD + j);
                    float f2 = ldf(feat, (size_t)s2 * FD + j);
                    float f3 = ldf(feat, (size_t)s3 * FD + j);
                    float f4 = ldf(feat, (size_t)s4 * FD + j);
                    float f5 = ldf(feat, (size_t)s5 * FD + j);
                    float f6 = ldf(feat, (size_t)s6 * FD + j);
                    float f7 = ldf(feat, (size_t)s7 * FD + j);
                    acc += c_src[s0] * f0 + c_src[s1] * f1 + c_src[s2] * f2 + c_src[s3] * f3;
                    acc += c_src[s4] * f4 + c_src[s5] * f5 + c_src[s6] * f6 + c_src[s7] * f7;
                }
                for (; q + 4 <= end; q += 4) {   // x4 mid-tier
                    unsigned s0 = col[q], s1 = col[q + 1], s2 = col[q + 2], s3 = col[q + 3];
                    float f0 = ldf(feat, (size_t)s0 * FD + j);
                    float f1 = ldf(feat, (size_t)s1 * FD + j);
                    float f2 = ldf(feat, (size_t)s2 * FD + j);
                    float f3 = ldf(feat, (size_t)s3 * FD + j);
                    acc += c_src[s0] * f0 + c_src[s1] * f1 + c_src[s2] * f2 + c_src[s3] * f3;
                }
                for (; q < end; q++) {
                    unsigned s = col[q];
                    acc += c_src[s] * ldf(feat, (size_t)s * FD + j);
                }
            }
            xs[r][j] = acc;
        }
        __syncthreads();
        // ---- GEMM: half h computes rows 2h, 2h+1 for its feature j; k-blocked x4 ----
        const float* x0 = xs[half * 2];
        const float* x1 = xs[half * 2 + 1];
        float d0 = 0.0f, d1 = 0.0f;
        for (int k = 0; k < FD; k += 4) {
            float4 a0 = *(const float4*)&x0[k];   // broadcast b128, conflict-free
            float4 a1 = *(const float4*)&x1[k];
            float w0 = b2f(Wl[(k + 0) * FD + j]);
            float w1 = b2f(Wl[(k + 1) * FD + j]);
            float w2 = b2f(Wl[(k + 2) * FD + j]);
            float w3 = b2f(Wl[(k + 3) * FD + j]);
            d0 += a0.x * w0 + a0.y * w1 + a0.z * w2 + a0.w * w3;
            d1 += a1.x * w0 + a1.y * w1 + a1.z * w2 + a1.w * w3;
        }
        int n0 = base + p * 4 + half * 2;
        int n1 = n0 + 1;
        if (n0 < n) {
            float h0 = fmaxf(d0 * c_dst[n0] + b1l[j], 0.0f);
            psum += h0 * wsum[n0] * c_src[n0];
        }
        if (n1 < n) {
            float h1 = fmaxf(d1 * c_dst[n1] + b1l[j], 0.0f);
            psum += h1 * wsum[n1] * c_src[n1];
        }
        __syncthreads();
    }
    part[half][j] = psum;
    __syncthreads();
    if (t < FD) unsafeAtomicAdd(&accum128[t], part[0][t] + part[1][t]);
}

// ---------- final tiny GEMM: out = (accum128/N) @ W2 + b2 ----------
template <typename T, typename TO>
__global__ void k_final(const unsigned* __restrict__ flag, unsigned want,
                        const float* __restrict__ accum128,
                        const T* __restrict__ W2, const T* __restrict__ b2v,
                        TO* __restrict__ out, float invN) {
    if (*flag != want) return;
    int j = threadIdx.x;   // 64 threads
    float acc = 0.0f;
    for (int k = 0; k < FD; k++) acc += accum128[k] * ldf(W2, (size_t)k * OD + j);
    float v = acc * invN + ldf(b2v, j);
    if constexpr (sizeof(TO) == 2) out[j] = __float2bfloat16(v);
    else                           out[j] = (TO)v;
}

extern "C" void kernel_launch(void* const* d_in, const int* in_sizes, int n_in,
                              void* d_out, int out_size, void* d_ws, size_t ws_size,
                              hipStream_t stream) {
    const int* src = (const int*)d_in[1];
    const int* dst = (const int*)d_in[2];
    int N = in_sizes[0] / FD;
    int E = in_sizes[1];

    char* ws = (char*)d_ws;
    unsigned* flag     = (unsigned*)(ws);
    float*    accum128 = (float*)   (ws + 1024);
    unsigned* bsum     = (unsigned*)(ws + 4096);
    unsigned* bpre     = (unsigned*)(ws + 8192);
    unsigned* deg_s    = (unsigned*)(ws + 16384);
    unsigned* deg_d    = (unsigned*)(ws + 524288);
    float*    c_src    = (float*)   (ws + 1048576);
    float*    c_dst    = (float*)   (ws + 1572864);
    float*    wsum     = (float*)   (ws + 2097152);
    unsigned* row_ptr  = (unsigned*)(ws + 2621440);
    unsigned* cursor   = (unsigned*)(ws + 3145728);
    unsigned* col      = (unsigned*)(ws + 3670016);
    // total footprint: 3670016 + E*4 = ~10.1 MB

    hipMemsetAsync(deg_s, 0, (size_t)N * 4, stream);
    hipMemsetAsync(deg_d, 0, (size_t)N * 4, stream);
    hipMemsetAsync(wsum,  0, (size_t)N * 4, stream);
    hipMemsetAsync(accum128, 0, FD * 4, stream);

    int nb = (N + 255) / 256;   // 391 <= 512

    k_sniff<<<1, 64, 0, stream>>>((const unsigned short*)d_in[3], flag);
    k_deg<<<(E + 255) / 256, 256, 0, stream>>>(src, dst, deg_s, deg_d, E);
    k_cnorm<<<nb, 256, 0, stream>>>(deg_s, deg_d, c_src, c_dst, N);
    k_wsum<<<(E + 255) / 256, 256, 0, stream>>>(src, dst, c_dst, wsum, E);
    k_scan1<<<nb, 256, 0, stream>>>(deg_d, bsum, N);
    k_scan2<<<1, 512, 0, stream>>>(bsum, bpre, nb);
    k_scan3<<<nb, 256, 0, stream>>>(deg_d, bpre, row_ptr, cursor, N, E);
    k_fill<<<(E + 255) / 256, 256, 0, stream>>>(src, dst, cursor, col, E);

    int gl1 = (N + 63) / 64;
    k_layer1<bf16><<<gl1, 256, 0, stream>>>(flag, 0u, (const bf16*)d_in[0], (const bf16*)d_in[3],
                                            (const bf16*)d_in[4], c_src, c_dst, wsum,
                                            row_ptr, col, accum128, N);
    k_layer1<float><<<gl1, 256, 0, stream>>>(flag, 1u, (const float*)d_in[0], (const float*)d_in[3],
                                             (const float*)d_in[4], c_src, c_dst, wsum,
                                             row_ptr, col, accum128, N);

    float invN = 1.0f / (float)N;
    k_final<bf16, bf16><<<1, 64, 0, stream>>>(flag, 0u, accum128, (const bf16*)d_in[5],
                                              (const bf16*)d_in[6], (bf16*)d_out, invN);
    k_final<float, float><<<1, 64, 0, stream>>>(flag, 1u, accum128, (const float*)d_in[5],
                                                (const float*)d_in[6], (float*)d_out, invN);
}

// Round 10
// 675.612 us; speedup vs baseline: 1.9272x; 1.9272x over previous
//
#include <hip/hip_runtime.h>
#include <hip/hip_bf16.h>

#define FD 128   // IN == HID == 128
#define OD 64    // OUT

typedef __hip_bfloat16 bf16;
typedef unsigned int u32;

__device__ __forceinline__ float b2f(bf16 x) { return __bfloat162float(x); }
__device__ __forceinline__ float ldf(const float* p, size_t i) { return p[i]; }
__device__ __forceinline__ float ldf(const bf16* p, size_t i) { return __bfloat162float(p[i]); }
__device__ __forceinline__ float us2f(unsigned short u) {
    union { float f; u32 i; } w; w.i = ((u32)u) << 16; return w.f;
}
// load 2 consecutive elements (bf16 world: single aligned 4B uint load)
template <typename T>
__device__ __forceinline__ void ld2(const T* p, size_t i, float& a, float& b) {
    if constexpr (sizeof(T) == 2) {
        u32 v = *(const u32*)((const unsigned short*)p + i);   // i is even -> 4B aligned
        a = us2f((unsigned short)(v & 0xffff));
        b = us2f((unsigned short)(v >> 16));
    } else {
        a = p[i]; b = p[i + 1];
    }
}

// ---------- dtype sniffer: bf16 data -> sane exponents; fp32 read as u16 -> garbage ----------
__global__ void k_sniff(const unsigned short* w1raw, unsigned* flag) {
    int t = threadIdx.x;                 // 64 threads
    int insane = 0;
    for (int i = t; i < 128; i += 64) {
        unsigned e = (w1raw[i] >> 7) & 0xFF;
        if (e != 0 && (e < 100 || e > 140)) insane++;
    }
    for (int o = 32; o > 0; o >>= 1) insane += __shfl_down(insane, o);
    if (t == 0) *flag = (insane > 16) ? 1u : 0u;   // 0 = bf16 world, 1 = fp32 world
}

// ---------- degree count ----------
__global__ void k_deg(const int* __restrict__ src, const int* __restrict__ dst,
                      unsigned* __restrict__ deg_s, unsigned* __restrict__ deg_d, int E) {
    int i = blockIdx.x * blockDim.x + threadIdx.x;
    if (i < E) {
        atomicAdd(&deg_s[src[i]], 1u);
        atomicAdd(&deg_d[dst[i]], 1u);
    }
}

// ---------- c = rsqrt(max(deg,1)) ----------
__global__ void k_cnorm(const unsigned* __restrict__ deg_s, const unsigned* __restrict__ deg_d,
                        float* __restrict__ c_src, float* __restrict__ c_dst, int n) {
    int i = blockIdx.x * blockDim.x + threadIdx.x;
    if (i < n) {
        c_src[i] = rsqrtf(fmaxf((float)deg_s[i], 1.0f));
        c_dst[i] = rsqrtf(fmaxf((float)deg_d[i], 1.0f));
    }
}

// ---------- wsum[s] = sum over out-edges of c_dst[dst] ----------
__global__ void k_wsum(const int* __restrict__ src, const int* __restrict__ dst,
                       const float* __restrict__ c_dst, float* __restrict__ wsum, int E) {
    int e = blockIdx.x * blockDim.x + threadIdx.x;
    if (e < E) unsafeAtomicAdd(&wsum[src[e]], c_dst[dst[e]]);
}

// ---------- scan stage 1: per-block sums of in-degree ----------
__global__ void k_scan1(const unsigned* __restrict__ deg, unsigned* __restrict__ bsum, int n) {
    __shared__ unsigned red[256];
    int t = threadIdx.x, i = blockIdx.x * 256 + t;
    red[t] = (i < n) ? deg[i] : 0u;
    __syncthreads();
    for (int o = 128; o > 0; o >>= 1) {
        if (t < o) red[t] += red[t + o];
        __syncthreads();
    }
    if (t == 0) bsum[blockIdx.x] = red[0];
}

// ---------- scan stage 2: exclusive scan of block sums (single block, 512 thr) ----------
__global__ void k_scan2(const unsigned* __restrict__ bsum, unsigned* __restrict__ bpre, int nb) {
    __shared__ unsigned s[512];
    int t = threadIdx.x;
    unsigned v = (t < nb) ? bsum[t] : 0u;
    s[t] = v;
    __syncthreads();
    for (int o = 1; o < 512; o <<= 1) {
        unsigned x = (t >= o) ? s[t - o] : 0u;
        __syncthreads();
        s[t] += x;
        __syncthreads();
    }
    if (t < nb) bpre[t] = s[t] - v;
}

// ---------- scan stage 3: row_ptr + cursor ----------
__global__ void k_scan3(const unsigned* __restrict__ deg, const unsigned* __restrict__ bpre,
                        unsigned* __restrict__ row_ptr, unsigned* __restrict__ cursor,
                        int n, int E) {
    __shared__ unsigned s[256];
    int t = threadIdx.x, i = blockIdx.x * 256 + t;
    unsigned v = (i < n) ? deg[i] : 0u;
    s[t] = v;
    __syncthreads();
    for (int o = 1; o < 256; o <<= 1) {
        unsigned x = (t >= o) ? s[t - o] : 0u;
        __syncthreads();
        s[t] += x;
        __syncthreads();
    }
    unsigned excl = bpre[blockIdx.x] + s[t] - v;
    if (i < n) { row_ptr[i] = excl; cursor[i] = excl; }
    if (blockIdx.x == 0 && t == 0) row_ptr[n] = (unsigned)E;
}

// ---------- CSR fill: col[] = src sorted by dst ----------
__global__ void k_fill(const int* __restrict__ src, const int* __restrict__ dst,
                       unsigned* __restrict__ cursor, unsigned* __restrict__ col, int E) {
    int e = blockIdx.x * blockDim.x + threadIdx.x;
    if (e < E) {
        unsigned p = atomicAdd(&cursor[dst[e]], 1u);
        col[p] = (unsigned)src[e];
    }
}

// ---------- layer1 fused: one wave per node, no inner barriers ----------
// Wave w owns nodes [base+16w, base+16w+16); lane jp owns features 2jp, 2jp+1.
// Gather: 1 uint (2 bf16) load per edge per lane, x4 unrolled.
// GEMM per 4 k: 1 broadcast float4 xs read + 4 uint W reads (bank jp%32) = 5 LDS / 8 MACs.
template <typename T>
__global__ __launch_bounds__(256) void k_layer1(const unsigned* __restrict__ flag, unsigned want,
                                                const T* __restrict__ feat, const T* __restrict__ W1,
                                                const T* __restrict__ b1,
                                                const float* __restrict__ c_src,
                                                const float* __restrict__ c_dst,
                                                const float* __restrict__ wsum,
                                                const unsigned* __restrict__ row_ptr,
                                                const unsigned* __restrict__ col,
                                                float* __restrict__ accum128, int n) {
    if (*flag != want) return;
    __shared__ __align__(16) bf16 Wl[FD * FD];   // 32 KB, uint-read below (4B aligned)
    __shared__ float b1l[FD];
    __shared__ __align__(16) float xs[4][FD];    // wave-private rows, float4-read
    __shared__ float part[4][FD];
    int t = threadIdx.x;
    for (int i = t; i < FD * FD; i += 256) Wl[i] = __float2bfloat16(ldf(W1, i));
    if (t < FD) b1l[t] = ldf(b1, t);
    __syncthreads();

    int jp = t & 63, w = t >> 6;
    int j0 = jp * 2;
    int base = blockIdx.x * 64 + w * 16;
    float psum0 = 0.0f, psum1 = 0.0f;
    float* xr = xs[w];

    for (int p = 0; p < 16; p++) {
        int node = base + p;
        // ---- gather: whole wave loads this node's in-neighbors (coalesced 256B rows) ----
        float acc0 = 0.0f, acc1 = 0.0f;
        if (node < n) {
            unsigned q = row_ptr[node], qe = row_ptr[node + 1];
            for (; q + 4 <= qe; q += 4) {     // 4 independent 4B loads in flight per lane
                unsigned s0 = col[q], s1 = col[q + 1], s2 = col[q + 2], s3 = col[q + 3];
                float a0, b0, a1, b1v, a2, b2, a3, b3;
                ld2(feat, (size_t)s0 * FD + j0, a0, b0);
                ld2(feat, (size_t)s1 * FD + j0, a1, b1v);
                ld2(feat, (size_t)s2 * FD + j0, a2, b2);
                ld2(feat, (size_t)s3 * FD + j0, a3, b3);
                float c0 = c_src[s0], c1 = c_src[s1], c2 = c_src[s2], c3 = c_src[s3];
                acc0 += c0 * a0 + c1 * a1 + c2 * a2 + c3 * a3;
                acc1 += c0 * b0 + c1 * b1v + c2 * b2 + c3 * b3;
            }
            for (; q < qe; q++) {
                unsigned s = col[q];
                float a, b;
                ld2(feat, (size_t)s * FD + j0, a, b);
                float c = c_src[s];
                acc0 += c * a;
                acc1 += c * b;
            }
        }
        xr[j0] = acc0;
        xr[j0 + 1] = acc1;                    // wave-private: no barrier needed
        // ---- GEMM: d[j0], d[j0+1] = xr . W[:,j0], W[:,j0+1] ----
        float d0 = 0.0f, d1 = 0.0f;
        for (int k = 0; k < FD; k += 4) {
            float4 a = *(const float4*)&xr[k];                 // broadcast, conflict-free
            u32 w0 = *(const u32*)&Wl[(k + 0) * FD + j0];      // bank = jp%32, 2-way free
            u32 w1 = *(const u32*)&Wl[(k + 1) * FD + j0];
            u32 w2 = *(const u32*)&Wl[(k + 2) * FD + j0];
            u32 w3 = *(const u32*)&Wl[(k + 3) * FD + j0];
            d0 += a.x * us2f((unsigned short)(w0 & 0xffff));
            d1 += a.x * us2f((unsigned short)(w0 >> 16));
            d0 += a.y * us2f((unsigned short)(w1 & 0xffff));
            d1 += a.y * us2f((unsigned short)(w1 >> 16));
            d0 += a.z * us2f((unsigned short)(w2 & 0xffff));
            d1 += a.z * us2f((unsigned short)(w2 >> 16));
            d0 += a.w * us2f((unsigned short)(w3 & 0xffff));
            d1 += a.w * us2f((unsigned short)(w3 >> 16));
        }
        if (node < n) {
            float cd = c_dst[node];
            float wc = wsum[node] * c_src[node];
            psum0 += wc * fmaxf(d0 * cd + b1l[j0], 0.0f);
            psum1 += wc * fmaxf(d1 * cd + b1l[j0 + 1], 0.0f);
        }
    }
    part[w][j0] = psum0;
    part[w][j0 + 1] = psum1;
    __syncthreads();
    if (t < FD) {
        float v = part[0][t] + part[1][t] + part[2][t] + part[3][t];
        unsafeAtomicAdd(&accum128[t], v);
    }
}

// ---------- final tiny GEMM: out = (accum128/N) @ W2 + b2 ----------
template <typename T, typename TO>
__global__ void k_final(const unsigned* __restrict__ flag, unsigned want,
                        const float* __restrict__ accum128,
                        const T* __restrict__ W2, const T* __restrict__ b2v,
                        TO* __restrict__ out, float invN) {
    if (*flag != want) return;
    int j = threadIdx.x;   // 64 threads
    float acc = 0.0f;
    for (int k = 0; k < FD; k++) acc += accum128[k] * ldf(W2, (size_t)k * OD + j);
    float v = acc * invN + ldf(b2v, j);
    if constexpr (sizeof(TO) == 2) out[j] = __float2bfloat16(v);
    else                           out[j] = (TO)v;
}

extern "C" void kernel_launch(void* const* d_in, const int* in_sizes, int n_in,
                              void* d_out, int out_size, void* d_ws, size_t ws_size,
                              hipStream_t stream) {
    const int* src = (const int*)d_in[1];
    const int* dst = (const int*)d_in[2];
    int N = in_sizes[0] / FD;
    int E = in_sizes[1];

    char* ws = (char*)d_ws;
    unsigned* flag     = (unsigned*)(ws);
    float*    accum128 = (float*)   (ws + 1024);
    unsigned* bsum     = (unsigned*)(ws + 4096);
    unsigned* bpre     = (unsigned*)(ws + 8192);
    unsigned* deg_s    = (unsigned*)(ws + 16384);
    unsigned* deg_d    = (unsigned*)(ws + 524288);
    float*    c_src    = (float*)   (ws + 1048576);
    float*    c_dst    = (float*)   (ws + 1572864);
    float*    wsum     = (float*)   (ws + 2097152);
    unsigned* row_ptr  = (unsigned*)(ws + 2621440);
    unsigned* cursor   = (unsigned*)(ws + 3145728);
    unsigned* col      = (unsigned*)(ws + 3670016);
    // total footprint: 3670016 + E*4 = ~10.1 MB

    hipMemsetAsync(deg_s, 0, (size_t)N * 4, stream);
    hipMemsetAsync(deg_d, 0, (size_t)N * 4, stream);
    hipMemsetAsync(wsum,  0, (size_t)N * 4, stream);
    hipMemsetAsync(accum128, 0, FD * 4, stream);

    int nb = (N + 255) / 256;   // 391 <= 512

    k_sniff<<<1, 64, 0, stream>>>((const unsigned short*)d_in[3], flag);
    k_deg<<<(E + 255) / 256, 256, 0, stream>>>(src, dst, deg_s, deg_d, E);
    k_cnorm<<<nb, 256, 0, stream>>>(deg_s, deg_d, c_src, c_dst, N);
    k_wsum<<<(E + 255) / 256, 256, 0, stream>>>(src, dst, c_dst, wsum, E);
    k_scan1<<<nb, 256, 0, stream>>>(deg_d, bsum, N);
    k_scan2<<<1, 512, 0, stream>>>(bsum, bpre, nb);
    k_scan3<<<nb, 256, 0, stream>>>(deg_d, bpre, row_ptr, cursor, N, E);
    k_fill<<<(E + 255) / 256, 256, 0, stream>>>(src, dst, cursor, col, E);

    int gl1 = (N + 63) / 64;
    k_layer1<bf16><<<gl1, 256, 0, stream>>>(flag, 0u, (const bf16*)d_in[0], (const bf16*)d_in[3],
                                            (const bf16*)d_in[4], c_src, c_dst, wsum,
                                            row_ptr, col, accum128, N);
    k_layer1<float><<<gl1, 256, 0, stream>>>(flag, 1u, (const float*)d_in[0], (const float*)d_in[3],
                                             (const float*)d_in[4], c_src, c_dst, wsum,
                                             row_ptr, col, accum128, N);

    float invN = 1.0f / (float)N;
    k_final<bf16, bf16><<<1, 64, 0, stream>>>(flag, 0u, accum128, (const bf16*)d_in[5],
                                              (const bf16*)d_in[6], (bf16*)d_out, invN);
    k_final<float, float><<<1, 64, 0, stream>>>(flag, 1u, accum128, (const float*)d_in[5],
                                                (const float*)d_in[6], (float*)d_out, invN);
}

// Round 11
// 647.053 us; speedup vs baseline: 2.0123x; 1.0441x over previous
//
#include <hip/hip_runtime.h>
#include <hip/hip_bf16.h>

#define FD 128   // IN == HID == 128
#define OD 64    // OUT

typedef __hip_bfloat16 bf16;
typedef unsigned int u32;

__device__ __forceinline__ float b2f(bf16 x) { return __bfloat162float(x); }
__device__ __forceinline__ float ldf(const float* p, size_t i) { return p[i]; }
__device__ __forceinline__ float ldf(const bf16* p, size_t i) { return __bfloat162float(p[i]); }
__device__ __forceinline__ float us2f(unsigned short u) {
    union { float f; u32 i; } w; w.i = ((u32)u) << 16; return w.f;
}
// load 2 consecutive elements (bf16 world: single aligned 4B uint load)
template <typename T>
__device__ __forceinline__ void ld2(const T* p, size_t i, float& a, float& b) {
    if constexpr (sizeof(T) == 2) {
        u32 v = *(const u32*)((const unsigned short*)p + i);   // i is even -> 4B aligned
        a = us2f((unsigned short)(v & 0xffff));
        b = us2f((unsigned short)(v >> 16));
    } else {
        a = p[i]; b = p[i + 1];
    }
}

// ---------- dtype sniffer: bf16 data -> sane exponents; fp32 read as u16 -> garbage ----------
__global__ void k_sniff(const unsigned short* w1raw, unsigned* flag) {
    int t = threadIdx.x;                 // 64 threads
    int insane = 0;
    for (int i = t; i < 128; i += 64) {
        unsigned e = (w1raw[i] >> 7) & 0xFF;
        if (e != 0 && (e < 100 || e > 140)) insane++;
    }
    for (int o = 32; o > 0; o >>= 1) insane += __shfl_down(insane, o);
    if (t == 0) *flag = (insane > 16) ? 1u : 0u;   // 0 = bf16 world, 1 = fp32 world
}

// ---------- degree count ----------
__global__ void k_deg(const int* __restrict__ src, const int* __restrict__ dst,
                      unsigned* __restrict__ deg_s, unsigned* __restrict__ deg_d, int E) {
    int i = blockIdx.x * blockDim.x + threadIdx.x;
    if (i < E) {
        atomicAdd(&deg_s[src[i]], 1u);
        atomicAdd(&deg_d[dst[i]], 1u);
    }
}

// ---------- scan stage 1 FUSED with cnorm: c=rsqrt(max(deg,1)) + per-block sums of deg_d ----------
__global__ void k_scan1(const unsigned* __restrict__ deg_s, const unsigned* __restrict__ deg_d,
                        float* __restrict__ c_src, float* __restrict__ c_dst,
                        unsigned* __restrict__ bsum, int n) {
    __shared__ unsigned red[256];
    int t = threadIdx.x, i = blockIdx.x * 256 + t;
    unsigned v = 0u;
    if (i < n) {
        unsigned ds = deg_s[i];
        v = deg_d[i];
        c_src[i] = rsqrtf(fmaxf((float)ds, 1.0f));
        c_dst[i] = rsqrtf(fmaxf((float)v, 1.0f));
    }
    red[t] = v;
    __syncthreads();
    for (int o = 128; o > 0; o >>= 1) {
        if (t < o) red[t] += red[t + o];
        __syncthreads();
    }
    if (t == 0) bsum[blockIdx.x] = red[0];
}

// ---------- scan stage 2: exclusive scan of block sums (single block, 512 thr) ----------
__global__ void k_scan2(const unsigned* __restrict__ bsum, unsigned* __restrict__ bpre, int nb) {
    __shared__ unsigned s[512];
    int t = threadIdx.x;
    unsigned v = (t < nb) ? bsum[t] : 0u;
    s[t] = v;
    __syncthreads();
    for (int o = 1; o < 512; o <<= 1) {
        unsigned x = (t >= o) ? s[t - o] : 0u;
        __syncthreads();
        s[t] += x;
        __syncthreads();
    }
    if (t < nb) bpre[t] = s[t] - v;
}

// ---------- scan stage 3: row_ptr + cursor ----------
__global__ void k_scan3(const unsigned* __restrict__ deg, const unsigned* __restrict__ bpre,
                        unsigned* __restrict__ row_ptr, unsigned* __restrict__ cursor,
                        int n, int E) {
    __shared__ unsigned s[256];
    int t = threadIdx.x, i = blockIdx.x * 256 + t;
    unsigned v = (i < n) ? deg[i] : 0u;
    s[t] = v;
    __syncthreads();
    for (int o = 1; o < 256; o <<= 1) {
        unsigned x = (t >= o) ? s[t - o] : 0u;
        __syncthreads();
        s[t] += x;
        __syncthreads();
    }
    unsigned excl = bpre[blockIdx.x] + s[t] - v;
    if (i < n) { row_ptr[i] = excl; cursor[i] = excl; }
    if (blockIdx.x == 0 && t == 0) row_ptr[n] = (unsigned)E;
}

// ---------- CSR fill FUSED with wsum: col[] scatter + wsum[s] += c_dst[d] ----------
__global__ void k_fill(const int* __restrict__ src, const int* __restrict__ dst,
                       unsigned* __restrict__ cursor, unsigned* __restrict__ col,
                       const float* __restrict__ c_dst, float* __restrict__ wsum, int E) {
    int e = blockIdx.x * blockDim.x + threadIdx.x;
    if (e < E) {
        int s = src[e], d = dst[e];
        unsigned p = atomicAdd(&cursor[d], 1u);
        col[p] = (unsigned)s;
        unsafeAtomicAdd(&wsum[s], c_dst[d]);
    }
}

// ---------- layer1 fused: one wave per node-group, no inner barriers ----------
// Wave w owns nodes [base+16w, base+16w+16) in 4 groups of 4; lane jp owns features 2jp, 2jp+1.
// Gather (per node, unchanged from round 10): 1 uint (2 bf16) load per edge per lane, x4 unrolled.
// GEMM (NEW): 4 nodes share the W reads -> per 4-k: 4 b128 broadcasts + 4 b32 = 8 LDS / 32 MACs.
template <typename T>
__global__ __launch_bounds__(256) void k_layer1(const unsigned* __restrict__ flag, unsigned want,
                                                const T* __restrict__ feat, const T* __restrict__ W1,
                                                const T* __restrict__ b1,
                                                const float* __restrict__ c_src,
                                                const float* __restrict__ c_dst,
                                                const float* __restrict__ wsum,
                                                const unsigned* __restrict__ row_ptr,
                                                const unsigned* __restrict__ col,
                                                float* __restrict__ accum128, int n) {
    if (*flag != want) return;
    __shared__ __align__(16) bf16 Wl[FD * FD];    // 32 KB, uint-read below (4B aligned)
    __shared__ float b1l[FD];
    __shared__ __align__(16) float xs[4][4][FD];  // [wave][node-in-group][feat], 8 KB
    __shared__ float part[4][FD];
    int t = threadIdx.x;
    for (int i = t; i < FD * FD; i += 256) Wl[i] = __float2bfloat16(ldf(W1, i));
    if (t < FD) b1l[t] = ldf(b1, t);
    __syncthreads();

    int jp = t & 63, w = t >> 6;
    int j0 = jp * 2;
    int base = blockIdx.x * 64 + w * 16;
    float psum0 = 0.0f, psum1 = 0.0f;

    for (int pg = 0; pg < 4; pg++) {
        // ---- gather 4 nodes into this wave's private xs rows ----
        #pragma unroll
        for (int g = 0; g < 4; g++) {
            int node = base + pg * 4 + g;
            float acc0 = 0.0f, acc1 = 0.0f;
            if (node < n) {
                unsigned q = row_ptr[node], qe = row_ptr[node + 1];
                for (; q + 4 <= qe; q += 4) {     // 4 independent 4B loads in flight per lane
                    unsigned s0 = col[q], s1 = col[q + 1], s2 = col[q + 2], s3 = col[q + 3];
                    float a0, b0, a1, b1v, a2, b2, a3, b3;
                    ld2(feat, (size_t)s0 * FD + j0, a0, b0);
                    ld2(feat, (size_t)s1 * FD + j0, a1, b1v);
                    ld2(feat, (size_t)s2 * FD + j0, a2, b2);
                    ld2(feat, (size_t)s3 * FD + j0, a3, b3);
                    float c0 = c_src[s0], c1 = c_src[s1], c2 = c_src[s2], c3 = c_src[s3];
                    acc0 += c0 * a0 + c1 * a1 + c2 * a2 + c3 * a3;
                    acc1 += c0 * b0 + c1 * b1v + c2 * b2 + c3 * b3;
                }
                for (; q < qe; q++) {
                    unsigned s = col[q];
                    float a, b;
                    ld2(feat, (size_t)s * FD + j0, a, b);
                    float c = c_src[s];
                    acc0 += c * a;
                    acc1 += c * b;
                }
            }
            xs[w][g][j0] = acc0;
            xs[w][g][j0 + 1] = acc1;              // wave-private: no barrier needed
        }
        // ---- GEMM: 4 nodes share W reads; d[g][0..1] = xs[g] . W[:,j0..j0+1] ----
        float d00 = 0.0f, d01 = 0.0f, d10 = 0.0f, d11 = 0.0f;
        float d20 = 0.0f, d21 = 0.0f, d30 = 0.0f, d31 = 0.0f;
        for (int k = 0; k < FD; k += 4) {
            float4 a0 = *(const float4*)&xs[w][0][k];   // broadcast b128, conflict-free
            float4 a1 = *(const float4*)&xs[w][1][k];
            float4 a2 = *(const float4*)&xs[w][2][k];
            float4 a3 = *(const float4*)&xs[w][3][k];
            u32 w0 = *(const u32*)&Wl[(k + 0) * FD + j0];   // b32, conflict-free
            u32 w1 = *(const u32*)&Wl[(k + 1) * FD + j0];
            u32 w2 = *(const u32*)&Wl[(k + 2) * FD + j0];
            u32 w3 = *(const u32*)&Wl[(k + 3) * FD + j0];
            float wl0 = us2f((unsigned short)(w0 & 0xffff)), wh0 = us2f((unsigned short)(w0 >> 16));
            float wl1 = us2f((unsigned short)(w1 & 0xffff)), wh1 = us2f((unsigned short)(w1 >> 16));
            float wl2 = us2f((unsigned short)(w2 & 0xffff)), wh2 = us2f((unsigned short)(w2 >> 16));
            float wl3 = us2f((unsigned short)(w3 & 0xffff)), wh3 = us2f((unsigned short)(w3 >> 16));
            d00 += a0.x * wl0 + a0.y * wl1 + a0.z * wl2 + a0.w * wl3;
            d01 += a0.x * wh0 + a0.y * wh1 + a0.z * wh2 + a0.w * wh3;
            d10 += a1.x * wl0 + a1.y * wl1 + a1.z * wl2 + a1.w * wl3;
            d11 += a1.x * wh0 + a1.y * wh1 + a1.z * wh2 + a1.w * wh3;
            d20 += a2.x * wl0 + a2.y * wl1 + a2.z * wl2 + a2.w * wl3;
            d21 += a2.x * wh0 + a2.y * wh1 + a2.z * wh2 + a2.w * wh3;
            d30 += a3.x * wl0 + a3.y * wl1 + a3.z * wl2 + a3.w * wl3;
            d31 += a3.x * wh0 + a3.y * wh1 + a3.z * wh2 + a3.w * wh3;
        }
        float dg[4][2] = {{d00, d01}, {d10, d11}, {d20, d21}, {d30, d31}};
        #pragma unroll
        for (int g = 0; g < 4; g++) {
            int node = base + pg * 4 + g;
            if (node < n) {
                float cd = c_dst[node];
                float wc = wsum[node] * c_src[node];
                psum0 += wc * fmaxf(dg[g][0] * cd + b1l[j0], 0.0f);
                psum1 += wc * fmaxf(dg[g][1] * cd + b1l[j0 + 1], 0.0f);
            }
        }
    }
    part[w][j0] = psum0;
    part[w][j0 + 1] = psum1;
    __syncthreads();
    if (t < FD) {
        float v = part[0][t] + part[1][t] + part[2][t] + part[3][t];
        unsafeAtomicAdd(&accum128[t], v);
    }
}

// ---------- final tiny GEMM: out = (accum128/N) @ W2 + b2 ----------
template <typename T, typename TO>
__global__ void k_final(const unsigned* __restrict__ flag, unsigned want,
                        const float* __restrict__ accum128,
                        const T* __restrict__ W2, const T* __restrict__ b2v,
                        TO* __restrict__ out, float invN) {
    if (*flag != want) return;
    int j = threadIdx.x;   // 64 threads
    float acc = 0.0f;
    for (int k = 0; k < FD; k++) acc += accum128[k] * ldf(W2, (size_t)k * OD + j);
    float v = acc * invN + ldf(b2v, j);
    if constexpr (sizeof(TO) == 2) out[j] = __float2bfloat16(v);
    else                           out[j] = (TO)v;
}

extern "C" void kernel_launch(void* const* d_in, const int* in_sizes, int n_in,
                              void* d_out, int out_size, void* d_ws, size_t ws_size,
                              hipStream_t stream) {
    const int* src = (const int*)d_in[1];
    const int* dst = (const int*)d_in[2];
    int N = in_sizes[0] / FD;
    int E = in_sizes[1];

    char* ws = (char*)d_ws;
    unsigned* flag     = (unsigned*)(ws);
    float*    accum128 = (float*)   (ws + 1024);
    unsigned* bsum     = (unsigned*)(ws + 4096);
    unsigned* bpre     = (unsigned*)(ws + 8192);
    unsigned* deg_s    = (unsigned*)(ws + 16384);
    unsigned* deg_d    = (unsigned*)(ws + 524288);
    float*    c_src    = (float*)   (ws + 1048576);
    float*    c_dst    = (float*)   (ws + 1572864);
    float*    wsum     = (float*)   (ws + 2097152);
    unsigned* row_ptr  = (unsigned*)(ws + 2621440);
    unsigned* cursor   = (unsigned*)(ws + 3145728);
    unsigned* col      = (unsigned*)(ws + 3670016);
    // total footprint: 3670016 + E*4 = ~10.1 MB

    hipMemsetAsync(deg_s, 0, (size_t)N * 4, stream);
    hipMemsetAsync(deg_d, 0, (size_t)N * 4, stream);
    hipMemsetAsync(wsum,  0, (size_t)N * 4, stream);
    hipMemsetAsync(accum128, 0, FD * 4, stream);

    int nb = (N + 255) / 256;   // 391 <= 512

    k_sniff<<<1, 64, 0, stream>>>((const unsigned short*)d_in[3], flag);
    k_deg<<<(E + 255) / 256, 256, 0, stream>>>(src, dst, deg_s, deg_d, E);
    k_scan1<<<nb, 256, 0, stream>>>(deg_s, deg_d, c_src, c_dst, bsum, N);
    k_scan2<<<1, 512, 0, stream>>>(bsum, bpre, nb);
    k_scan3<<<nb, 256, 0, stream>>>(deg_d, bpre, row_ptr, cursor, N, E);
    k_fill<<<(E + 255) / 256, 256, 0, stream>>>(src, dst, cursor, col, c_dst, wsum, E);

    int gl1 = (N + 63) / 64;
    k_layer1<bf16><<<gl1, 256, 0, stream>>>(flag, 0u, (const bf16*)d_in[0], (const bf16*)d_in[3],
                                            (const bf16*)d_in[4], c_src, c_dst, wsum,
                                            row_ptr, col, accum128, N);
    k_layer1<float><<<gl1, 256, 0, stream>>>(flag, 1u, (const float*)d_in[0], (const float*)d_in[3],
                                             (const float*)d_in[4], c_src, c_dst, wsum,
                                             row_ptr, col, accum128, N);

    float invN = 1.0f / (float)N;
    k_final<bf16, bf16><<<1, 64, 0, stream>>>(flag, 0u, accum128, (const bf16*)d_in[5],
                                              (const bf16*)d_in[6], (bf16*)d_out, invN);
    k_final<float, float><<<1, 64, 0, stream>>>(flag, 1u, accum128, (const float*)d_in[5],
                                                (const float*)d_in[6], (float*)d_out, invN);
}

// Round 12
// 576.092 us; speedup vs baseline: 2.2602x; 1.1232x over previous
//
#include <hip/hip_runtime.h>
#include <hip/hip_bf16.h>

#define FD 128   // IN == HID == 128
#define OD 64    // OUT

typedef __hip_bfloat16 bf16;
typedef unsigned int u32;

__device__ __forceinline__ float b2f(bf16 x) { return __bfloat162float(x); }
__device__ __forceinline__ float ldf(const float* p, size_t i) { return p[i]; }
__device__ __forceinline__ float ldf(const bf16* p, size_t i) { return __bfloat162float(p[i]); }
__device__ __forceinline__ float us2f(unsigned short u) {
    union { float f; u32 i; } w; w.i = ((u32)u) << 16; return w.f;
}
// load 2 consecutive elements (bf16 world: single aligned 4B uint load)
template <typename T>
__device__ __forceinline__ void ld2(const T* p, size_t i, float& a, float& b) {
    if constexpr (sizeof(T) == 2) {
        u32 v = *(const u32*)((const unsigned short*)p + i);   // i is even -> 4B aligned
        a = us2f((unsigned short)(v & 0xffff));
        b = us2f((unsigned short)(v >> 16));
    } else {
        a = p[i]; b = p[i + 1];
    }
}

// ---------- dtype sniffer: bf16 data -> sane exponents; fp32 read as u16 -> garbage ----------
__global__ void k_sniff(const unsigned short* w1raw, unsigned* flag) {
    int t = threadIdx.x;                 // 64 threads
    int insane = 0;
    for (int i = t; i < 128; i += 64) {
        unsigned e = (w1raw[i] >> 7) & 0xFF;
        if (e != 0 && (e < 100 || e > 140)) insane++;
    }
    for (int o = 32; o > 0; o >>= 1) insane += __shfl_down(insane, o);
    if (t == 0) *flag = (insane > 16) ? 1u : 0u;   // 0 = bf16 world, 1 = fp32 world
}

// ---------- degree count ----------
__global__ void k_deg(const int* __restrict__ src, const int* __restrict__ dst,
                      unsigned* __restrict__ deg_s, unsigned* __restrict__ deg_d, int E) {
    int i = blockIdx.x * blockDim.x + threadIdx.x;
    if (i < E) {
        atomicAdd(&deg_s[src[i]], 1u);
        atomicAdd(&deg_d[dst[i]], 1u);
    }
}

// ---------- scan stage 1 FUSED with cnorm: c=rsqrt(max(deg,1)) + per-block sums of deg_d ----------
__global__ void k_scan1(const unsigned* __restrict__ deg_s, const unsigned* __restrict__ deg_d,
                        float* __restrict__ c_src, float* __restrict__ c_dst,
                        unsigned* __restrict__ bsum, int n) {
    __shared__ unsigned red[256];
    int t = threadIdx.x, i = blockIdx.x * 256 + t;
    unsigned v = 0u;
    if (i < n) {
        unsigned ds = deg_s[i];
        v = deg_d[i];
        c_src[i] = rsqrtf(fmaxf((float)ds, 1.0f));
        c_dst[i] = rsqrtf(fmaxf((float)v, 1.0f));
    }
    red[t] = v;
    __syncthreads();
    for (int o = 128; o > 0; o >>= 1) {
        if (t < o) red[t] += red[t + o];
        __syncthreads();
    }
    if (t == 0) bsum[blockIdx.x] = red[0];
}

// ---------- scan stage 2: exclusive scan of block sums (single block, 512 thr) ----------
__global__ void k_scan2(const unsigned* __restrict__ bsum, unsigned* __restrict__ bpre, int nb) {
    __shared__ unsigned s[512];
    int t = threadIdx.x;
    unsigned v = (t < nb) ? bsum[t] : 0u;
    s[t] = v;
    __syncthreads();
    for (int o = 1; o < 512; o <<= 1) {
        unsigned x = (t >= o) ? s[t - o] : 0u;
        __syncthreads();
        s[t] += x;
        __syncthreads();
    }
    if (t < nb) bpre[t] = s[t] - v;
}

// ---------- scan stage 3: row_ptr + cursor ----------
__global__ void k_scan3(const unsigned* __restrict__ deg, const unsigned* __restrict__ bpre,
                        unsigned* __restrict__ row_ptr, unsigned* __restrict__ cursor,
                        int n, int E) {
    __shared__ unsigned s[256];
    int t = threadIdx.x, i = blockIdx.x * 256 + t;
    unsigned v = (i < n) ? deg[i] : 0u;
    s[t] = v;
    __syncthreads();
    for (int o = 1; o < 256; o <<= 1) {
        unsigned x = (t >= o) ? s[t - o] : 0u;
        __syncthreads();
        s[t] += x;
        __syncthreads();
    }
    unsigned excl = bpre[blockIdx.x] + s[t] - v;
    if (i < n) { row_ptr[i] = excl; cursor[i] = excl; }
    if (blockIdx.x == 0 && t == 0) row_ptr[n] = (unsigned)E;
}

// ---------- CSR fill FUSED with wsum: col[] scatter + wsum[s] += c_dst[d] ----------
__global__ void k_fill(const int* __restrict__ src, const int* __restrict__ dst,
                       unsigned* __restrict__ cursor, unsigned* __restrict__ col,
                       const float* __restrict__ c_dst, float* __restrict__ wsum, int E) {
    int e = blockIdx.x * blockDim.x + threadIdx.x;
    if (e < E) {
        int s = src[e], d = dst[e];
        unsigned p = atomicAdd(&cursor[d], 1u);
        col[p] = (unsigned)s;
        unsafeAtomicAdd(&wsum[s], c_dst[d]);
    }
}

// ---------- layer1 fused: one wave per node-group, no inner barriers ----------
// Wave w owns nodes [base+16w, base+16w+16) in 8 groups of 2; lane jp owns features 2jp, 2jp+1.
// Gather (per node, round-10/11 proven): 1 uint (2 bf16) load per edge per lane, x4 unrolled.
// GEMM: 2 nodes share W reads -> per 4-k: 2 b128 broadcasts + 4 b32 = 6 LDS / 16 MACs.
// LDS budget: W 32K + b1l 0.5K + xs 4K + part 2K = 38.5K -> 3 blocks/CU (vs 43.5K/2 in r11).
template <typename T>
__global__ __launch_bounds__(256) void k_layer1(const unsigned* __restrict__ flag, unsigned want,
                                                const T* __restrict__ feat, const T* __restrict__ W1,
                                                const T* __restrict__ b1,
                                                const float* __restrict__ c_src,
                                                const float* __restrict__ c_dst,
                                                const float* __restrict__ wsum,
                                                const unsigned* __restrict__ row_ptr,
                                                const unsigned* __restrict__ col,
                                                float* __restrict__ accum128, int n) {
    if (*flag != want) return;
    __shared__ __align__(16) bf16 Wl[FD * FD];    // 32 KB, uint-read below (4B aligned)
    __shared__ float b1l[FD];
    __shared__ __align__(16) float xs[4][2][FD];  // [wave][node-in-group][feat], 4 KB
    __shared__ float part[4][FD];
    int t = threadIdx.x;
    for (int i = t; i < FD * FD; i += 256) Wl[i] = __float2bfloat16(ldf(W1, i));
    if (t < FD) b1l[t] = ldf(b1, t);
    __syncthreads();

    int jp = t & 63, w = t >> 6;
    int j0 = jp * 2;
    int base = blockIdx.x * 64 + w * 16;
    float psum0 = 0.0f, psum1 = 0.0f;

    for (int pg = 0; pg < 8; pg++) {
        // ---- gather 2 nodes into this wave's private xs rows ----
        #pragma unroll
        for (int g = 0; g < 2; g++) {
            int node = base + pg * 2 + g;
            float acc0 = 0.0f, acc1 = 0.0f;
            if (node < n) {
                unsigned q = row_ptr[node], qe = row_ptr[node + 1];
                for (; q + 4 <= qe; q += 4) {     // 4 independent 4B loads in flight per lane
                    unsigned s0 = col[q], s1 = col[q + 1], s2 = col[q + 2], s3 = col[q + 3];
                    float a0, b0, a1, b1v, a2, b2, a3, b3;
                    ld2(feat, (size_t)s0 * FD + j0, a0, b0);
                    ld2(feat, (size_t)s1 * FD + j0, a1, b1v);
                    ld2(feat, (size_t)s2 * FD + j0, a2, b2);
                    ld2(feat, (size_t)s3 * FD + j0, a3, b3);
                    float c0 = c_src[s0], c1 = c_src[s1], c2 = c_src[s2], c3 = c_src[s3];
                    acc0 += c0 * a0 + c1 * a1 + c2 * a2 + c3 * a3;
                    acc1 += c0 * b0 + c1 * b1v + c2 * b2 + c3 * b3;
                }
                for (; q < qe; q++) {
                    unsigned s = col[q];
                    float a, b;
                    ld2(feat, (size_t)s * FD + j0, a, b);
                    float c = c_src[s];
                    acc0 += c * a;
                    acc1 += c * b;
                }
            }
            xs[w][g][j0] = acc0;
            xs[w][g][j0 + 1] = acc1;              // wave-private: no barrier needed
        }
        // ---- GEMM: 2 nodes share W reads ----
        float d00 = 0.0f, d01 = 0.0f, d10 = 0.0f, d11 = 0.0f;
        for (int k = 0; k < FD; k += 4) {
            float4 a0 = *(const float4*)&xs[w][0][k];   // broadcast b128, conflict-free
            float4 a1 = *(const float4*)&xs[w][1][k];
            u32 w0 = *(const u32*)&Wl[(k + 0) * FD + j0];   // b32, 2-way (free)
            u32 w1 = *(const u32*)&Wl[(k + 1) * FD + j0];
            u32 w2 = *(const u32*)&Wl[(k + 2) * FD + j0];
            u32 w3 = *(const u32*)&Wl[(k + 3) * FD + j0];
            float wl0 = us2f((unsigned short)(w0 & 0xffff)), wh0 = us2f((unsigned short)(w0 >> 16));
            float wl1 = us2f((unsigned short)(w1 & 0xffff)), wh1 = us2f((unsigned short)(w1 >> 16));
            float wl2 = us2f((unsigned short)(w2 & 0xffff)), wh2 = us2f((unsigned short)(w2 >> 16));
            float wl3 = us2f((unsigned short)(w3 & 0xffff)), wh3 = us2f((unsigned short)(w3 >> 16));
            d00 += a0.x * wl0 + a0.y * wl1 + a0.z * wl2 + a0.w * wl3;
            d01 += a0.x * wh0 + a0.y * wh1 + a0.z * wh2 + a0.w * wh3;
            d10 += a1.x * wl0 + a1.y * wl1 + a1.z * wl2 + a1.w * wl3;
            d11 += a1.x * wh0 + a1.y * wh1 + a1.z * wh2 + a1.w * wh3;
        }
        float dg[2][2] = {{d00, d01}, {d10, d11}};
        #pragma unroll
        for (int g = 0; g < 2; g++) {
            int node = base + pg * 2 + g;
            if (node < n) {
                float cd = c_dst[node];
                float wc = wsum[node] * c_src[node];
                psum0 += wc * fmaxf(dg[g][0] * cd + b1l[j0], 0.0f);
                psum1 += wc * fmaxf(dg[g][1] * cd + b1l[j0 + 1], 0.0f);
            }
        }
    }
    part[w][j0] = psum0;
    part[w][j0 + 1] = psum1;
    __syncthreads();
    if (t < FD) {
        float v = part[0][t] + part[1][t] + part[2][t] + part[3][t];
        unsafeAtomicAdd(&accum128[t], v);
    }
}

// ---------- final tiny GEMM: out = (accum128/N) @ W2 + b2 ----------
template <typename T, typename TO>
__global__ void k_final(const unsigned* __restrict__ flag, unsigned want,
                        const float* __restrict__ accum128,
                        const T* __restrict__ W2, const T* __restrict__ b2v,
                        TO* __restrict__ out, float invN) {
    if (*flag != want) return;
    int j = threadIdx.x;   // 64 threads
    float acc = 0.0f;
    for (int k = 0; k < FD; k++) acc += accum128[k] * ldf(W2, (size_t)k * OD + j);
    float v = acc * invN + ldf(b2v, j);
    if constexpr (sizeof(TO) == 2) out[j] = __float2bfloat16(v);
    else                           out[j] = (TO)v;
}

extern "C" void kernel_launch(void* const* d_in, const int* in_sizes, int n_in,
                              void* d_out, int out_size, void* d_ws, size_t ws_size,
                              hipStream_t stream) {
    const int* src = (const int*)d_in[1];
    const int* dst = (const int*)d_in[2];
    int N = in_sizes[0] / FD;
    int E = in_sizes[1];

    // workspace: zeroed region is one contiguous span [4096, 1048576 + N*4)
    char* ws = (char*)d_ws;
    unsigned* flag     = (unsigned*)(ws);
    float*    accum128 = (float*)   (ws + 4096);      // zeroed
    unsigned* deg_s    = (unsigned*)(ws + 65536);     // zeroed (N*4 <= 400KB)
    unsigned* deg_d    = (unsigned*)(ws + 524288);    // zeroed
    float*    wsum     = (float*)   (ws + 1048576);   // zeroed
    float*    c_src    = (float*)   (ws + 1572864);
    float*    c_dst    = (float*)   (ws + 2097152);
    unsigned* bsum     = (unsigned*)(ws + 2564096);
    unsigned* bpre     = (unsigned*)(ws + 2568192);
    unsigned* row_ptr  = (unsigned*)(ws + 2621440);
    unsigned* cursor   = (unsigned*)(ws + 3145728);
    unsigned* col      = (unsigned*)(ws + 3670016);
    // total footprint: 3670016 + E*4 = ~10.1 MB

    // single fused zero: accum128 + deg_s + deg_d + wsum (gaps harmlessly included)
    hipMemsetAsync(ws + 4096, 0, (size_t)(1048576 - 4096) + (size_t)N * 4, stream);

    int nb = (N + 255) / 256;   // 391 <= 512

    k_sniff<<<1, 64, 0, stream>>>((const unsigned short*)d_in[3], flag);
    k_deg<<<(E + 255) / 256, 256, 0, stream>>>(src, dst, deg_s, deg_d, E);
    k_scan1<<<nb, 256, 0, stream>>>(deg_s, deg_d, c_src, c_dst, bsum, N);
    k_scan2<<<1, 512, 0, stream>>>(bsum, bpre, nb);
    k_scan3<<<nb, 256, 0, stream>>>(deg_d, bpre, row_ptr, cursor, N, E);
    k_fill<<<(E + 255) / 256, 256, 0, stream>>>(src, dst, cursor, col, c_dst, wsum, E);

    int gl1 = (N + 63) / 64;
    k_layer1<bf16><<<gl1, 256, 0, stream>>>(flag, 0u, (const bf16*)d_in[0], (const bf16*)d_in[3],
                                            (const bf16*)d_in[4], c_src, c_dst, wsum,
                                            row_ptr, col, accum128, N);
    k_layer1<float><<<gl1, 256, 0, stream>>>(flag, 1u, (const float*)d_in[0], (const float*)d_in[3],
                                             (const float*)d_in[4], c_src, c_dst, wsum,
                                             row_ptr, col, accum128, N);

    float invN = 1.0f / (float)N;
    k_final<bf16, bf16><<<1, 64, 0, stream>>>(flag, 0u, accum128, (const bf16*)d_in[5],
                                              (const bf16*)d_in[6], (bf16*)d_out, invN);
    k_final<float, float><<<1, 64, 0, stream>>>(flag, 1u, accum128, (const float*)d_in[5],
                                                (const float*)d_in[6], (float*)d_out, invN);
}